// Round 2
// baseline (175.023 us; speedup 1.0000x reference)
//
#include <hip/hip_runtime.h>

#define BATCH 50
#define NATOMS 512
#define NBONDS 4096
#define ADJ_CAP 64

__device__ __forceinline__ float sigmoidf_(float x){ return 1.f/(1.f+__expf(-x)); }

// exact transcription of reference _taper
__device__ __forceinline__ float taperf_(float r, float rmin, float rmax){
    float r3  = (r > rmax) ? 1.f : 0.f;
    bool  ok  = (r <= rmax) && (r > rmin);
    float r2  = ok ? r   : 0.f;
    float r20 = ok ? 1.f : 0.f;
    float d   = rmin - rmax;
    float rterm = 1.f/(d*d*d);
    float rm  = rmin*r20;
    float rd  = rm - r2;
    float trm1 = rm + 2.f*r2 - 3.f*rmax*r20;
    return rterm*rd*rd*trm1 + r3;
}

// ---- prep: init only the table entries we will use, zero counts & out ----
__global__ __launch_bounds__(256) void init_kernel(const int* __restrict__ bdid,
                                                   unsigned* __restrict__ table,
                                                   unsigned* __restrict__ counts,
                                                   float* __restrict__ out){
    int k = blockIdx.x*256 + threadIdx.x;
    int i = bdid[2*k], j = bdid[2*k+1];
    table[i*NATOMS + j] = 0xFFFFFFFFu;
    if(k < NATOMS) counts[k] = 0u;
    if(k < BATCH)  out[k] = 0.f;
}

__global__ __launch_bounds__(256) void claim_kernel(const int* __restrict__ bdid,
                                                    unsigned* __restrict__ table){
    int k = blockIdx.x*256 + threadIdx.x;
    int i = bdid[2*k], j = bdid[2*k+1];
    atomicMin(&table[i*NATOMS + j], (unsigned)k);
}

// owned pairs -> adjacency (both directions). Avg degree ~16, cap 64.
__global__ __launch_bounds__(256) void fill_kernel(const int* __restrict__ bdid,
                                                   const unsigned* __restrict__ table,
                                                   unsigned* __restrict__ counts,
                                                   int* __restrict__ adj){
    int k = blockIdx.x*256 + threadIdx.x;
    int i = bdid[2*k], j = bdid[2*k+1];
    if(table[i*NATOMS + j] == (unsigned)k){
        unsigned ci = atomicAdd(&counts[i], 1u);
        if(ci < ADJ_CAP) adj[i*ADJ_CAP + ci] = j;
        unsigned cj = atomicAdd(&counts[j], 1u);
        if(cj < ADJ_CAP) adj[j*ADJ_CAP + cj] = i;
    }
}

// ---- bond MLP + ebond only; no scatter atomics ----
__global__ __launch_bounds__(256, 4) void bond_kernel(
    const float* __restrict__ x, const float* __restrict__ cell, const float* __restrict__ rcell,
    const float* __restrict__ gp, const float* __restrict__ bp,
    const float* __restrict__ fe_wi, const float* __restrict__ fe_w, const float* __restrict__ fe_b,
    const float* __restrict__ fe_wo, const float* __restrict__ fe_bo,
    const int* __restrict__ bdid,
    float* __restrict__ out)
{
    __shared__ __align__(16) float s_wi[24];
    __shared__ __align__(16) float s_w[320];
    __shared__ __align__(16) float s_bb[40];
    __shared__ __align__(16) float s_wo[8];
    __shared__ float s_cell[9], s_rcell[9];
    int tid = threadIdx.x;
    int b   = blockIdx.y;

    for(int t=tid;t<24;t+=256)  s_wi[t]=fe_wi[t];
    for(int t=tid;t<320;t+=256) s_w[t]=fe_w[t];
    for(int t=tid;t<40;t+=256)  s_bb[t]=fe_b[t];
    for(int t=tid;t<8;t+=256)   s_wo[t]=fe_wo[t];
    if(tid<9){ s_cell[tid]=cell[b*9+tid]; s_rcell[tid]=rcell[b*9+tid]; }
    __syncthreads();

    float botol = gp[6];
    float rosi=bp[0], ropi=bp[1], ropp=bp[2];
    float bo1=bp[3], bo2=bp[4], bo3=bp[5], bo4=bp[6], bo5=bp[7], bo6=bp[8], Desi=bp[9];
    float bo_out = fe_bo[0];

    int k = blockIdx.x*256 + tid;           // NBONDS == grid.x*256 exactly
    int i = bdid[2*k], j = bdid[2*k+1];
    const float* xb = x + (size_t)b*(NATOMS*3);
    float dx0 = xb[3*i+0]-xb[3*j+0];
    float dx1 = xb[3*i+1]-xb[3*j+1];
    float dx2 = xb[3*i+2]-xb[3*j+2];
    float f0 = dx0*s_rcell[0]+dx1*s_rcell[3]+dx2*s_rcell[6];
    float f1 = dx0*s_rcell[1]+dx1*s_rcell[4]+dx2*s_rcell[7];
    float f2 = dx0*s_rcell[2]+dx1*s_rcell[5]+dx2*s_rcell[8];
    f0 = (f0>0.5f)?f0-1.f:f0; f0 = (f0<-0.5f)?f0+1.f:f0;
    f1 = (f1>0.5f)?f1-1.f:f1; f1 = (f1<-0.5f)?f1+1.f:f1;
    f2 = (f2>0.5f)?f2-1.f:f2; f2 = (f2<-0.5f)?f2+1.f:f2;
    float v0 = f0*s_cell[0]+f1*s_cell[3]+f2*s_cell[6];
    float v1 = f0*s_cell[1]+f1*s_cell[4]+f2*s_cell[7];
    float v2 = f0*s_cell[2]+f1*s_cell[5]+f2*s_cell[8];
    float r = sqrtf(v0*v0+v1*v1+v2*v2);

    float eterm1 = (1.f+botol)*__expf(bo1*__powf(r/rosi, bo2));
    float eterm2 = __expf(bo3*__powf(r/ropi, bo4));
    float eterm3 = __expf(bo5*__powf(r/ropp, bo6));
    float tmax = 2.f*botol;
    float si = taperf_(eterm1, botol, tmax)*(eterm1-botol);
    float pi = taperf_(eterm2, botol, tmax)*eterm2;
    float pp = taperf_(eterm3, botol, tmax)*eterm3;

    // ---- MLP: 3 -> 8 -> (8x8)x5 -> 1, sigmoid everywhere ----
    float o[8];
    #pragma unroll
    for(int u=0;u<8;u++)
        o[u] = sigmoidf_(si*s_wi[u] + pi*s_wi[8+u] + pp*s_wi[16+u]);
    #pragma unroll
    for(int l=0;l<5;l++){
        float a[8];
        float4 bb0 = ((const float4*)(s_bb + l*8))[0];
        float4 bb1 = ((const float4*)(s_bb + l*8))[1];
        a[0]=bb0.x; a[1]=bb0.y; a[2]=bb0.z; a[3]=bb0.w;
        a[4]=bb1.x; a[5]=bb1.y; a[6]=bb1.z; a[7]=bb1.w;
        #pragma unroll
        for(int v=0;v<8;v++){
            const float4* wrow = (const float4*)(s_w + (l*8+v)*8);
            float4 w0 = wrow[0], w1 = wrow[1];
            float ov = o[v];
            a[0]=fmaf(ov,w0.x,a[0]); a[1]=fmaf(ov,w0.y,a[1]);
            a[2]=fmaf(ov,w0.z,a[2]); a[3]=fmaf(ov,w0.w,a[3]);
            a[4]=fmaf(ov,w1.x,a[4]); a[5]=fmaf(ov,w1.y,a[5]);
            a[6]=fmaf(ov,w1.z,a[6]); a[7]=fmaf(ov,w1.w,a[7]);
        }
        #pragma unroll
        for(int u=0;u<8;u++) o[u]=sigmoidf_(a[u]);
    }
    float4 wo0 = ((const float4*)s_wo)[0];
    float4 wo1 = ((const float4*)s_wo)[1];
    float acc = bo_out;
    acc = fmaf(o[0],wo0.x,acc); acc = fmaf(o[1],wo0.y,acc);
    acc = fmaf(o[2],wo0.z,acc); acc = fmaf(o[3],wo0.w,acc);
    acc = fmaf(o[4],wo1.x,acc); acc = fmaf(o[5],wo1.y,acc);
    acc = fmaf(o[6],wo1.z,acc); acc = fmaf(o[7],wo1.w,acc);
    float esi = sigmoidf_(acc);

    // ebond: wave shuffle reduce, one atomic per wave
    float e = -Desi*esi;
    #pragma unroll
    for(int off=32;off>0;off>>=1) e += __shfl_down(e, off, 64);
    if((tid & 63)==0) atomicAdd(&out[b], e);
}

// ---- atom-centric: recompute neighbor bop terms, no intermediate arrays ----
__global__ __launch_bounds__(64) void atom_kernel(
    const float* __restrict__ x, const float* __restrict__ cell, const float* __restrict__ rcell,
    const float* __restrict__ sp_p, const float* __restrict__ gp, const float* __restrict__ bp,
    const int* __restrict__ spec,
    const unsigned* __restrict__ counts, const int* __restrict__ adj,
    float* __restrict__ out)
{
    int tid = threadIdx.x;
    int n = blockIdx.x*64 + tid;
    int b = blockIdx.y;

    float c0=cell[b*9+0],c1=cell[b*9+1],c2=cell[b*9+2],
          c3=cell[b*9+3],c4=cell[b*9+4],c5=cell[b*9+5],
          c6=cell[b*9+6],c7=cell[b*9+7],c8=cell[b*9+8];
    float rc0=rcell[b*9+0],rc1=rcell[b*9+1],rc2=rcell[b*9+2],
          rc3=rcell[b*9+3],rc4=rcell[b*9+4],rc5=rcell[b*9+5],
          rc6=rcell[b*9+6],rc7=rcell[b*9+7],rc8=rcell[b*9+8];

    float botol = gp[6];
    float rosi=bp[0], ropi=bp[1], ropp=bp[2];
    float bo1=bp[3], bo2=bp[4], bo3=bp[5], bo4=bp[6], bo5=bp[7], bo6=bp[8];
    float tmax = 2.f*botol;

    const float* xb = x + (size_t)b*(NATOMS*3);
    float xi0 = xb[3*n+0], xi1 = xb[3*n+1], xi2 = xb[3*n+2];

    unsigned cnt = counts[n]; if(cnt > ADJ_CAP) cnt = ADJ_CAP;
    float D = 0.f, Dpi = 0.f, so = 0.f;
    for(unsigned c=0;c<cnt;c++){
        int m = adj[n*ADJ_CAP + c];
        float dx0 = xi0 - xb[3*m+0];
        float dx1 = xi1 - xb[3*m+1];
        float dx2 = xi2 - xb[3*m+2];
        float f0 = dx0*rc0+dx1*rc3+dx2*rc6;
        float f1 = dx0*rc1+dx1*rc4+dx2*rc7;
        float f2 = dx0*rc2+dx1*rc5+dx2*rc8;
        f0 = (f0>0.5f)?f0-1.f:f0; f0 = (f0<-0.5f)?f0+1.f:f0;
        f1 = (f1>0.5f)?f1-1.f:f1; f1 = (f1<-0.5f)?f1+1.f:f1;
        f2 = (f2>0.5f)?f2-1.f:f2; f2 = (f2<-0.5f)?f2+1.f:f2;
        float v0 = f0*c0+f1*c3+f2*c6;
        float v1 = f0*c1+f1*c4+f2*c7;
        float v2 = f0*c2+f1*c5+f2*c8;
        float r = sqrtf(v0*v0+v1*v1+v2*v2);

        float eterm1 = (1.f+botol)*__expf(bo1*__powf(r/rosi, bo2));
        float eterm2 = __expf(bo3*__powf(r/ropi, bo4));
        float eterm3 = __expf(bo5*__powf(r/ropp, bo6));
        float si = taperf_(eterm1, botol, tmax)*(eterm1-botol);
        float pi = taperf_(eterm2, botol, tmax)*eterm2;
        float pp = taperf_(eterm3, botol, tmax)*eterm3;
        D   += si+pi+pp;
        Dpi += pi+pp;
        so  += si;
    }

    float lp1=gp[0], ovun3=gp[1], ovun4=gp[2], ovun6=gp[3], ovun7=gp[4], ovun8=gp[5];
    int s = spec[n];
    float val  = sp_p[s*5+0], vale = sp_p[s*5+1], lp2 = sp_p[s*5+2];
    float ovun2= sp_p[s*5+3], ovun5= sp_p[s*5+4];

    float Nlp = 0.5f*(vale-val);
    float de  = 0.5f*(D-vale);
    float De  = fminf(ceilf(de), 0.f);          // -relu(-ceil(x)) == min(ceil(x),0)
    float t   = 1.f + de - De;
    float nlp = -De + __expf(-lp1*4.f*t*t);
    float Dlp = fmaxf(Nlp - nlp + 1.f, 0.f) - 1.f;
    float Elone = lp2*Dlp/(1.f+__expf(-75.f*Dlp));
    float dlp = D - val - Dlp/(1.f + ovun3*__expf(ovun4*Dpi));
    float denom = dlp + val;
    float otrm1 = 1.f/((denom!=0.f)?denom:1e-8f);
    float Eover = so*otrm1*dlp*sigmoidf_(-ovun2*dlp);
    float Eunder = -ovun5*(1.f-__expf(ovun6*dlp))*sigmoidf_(ovun2*dlp)
                   /(1.f + ovun7*__expf(ovun8*Dpi));

    float e = Elone + Eover + Eunder;
    #pragma unroll
    for(int off=32;off>0;off>>=1) e += __shfl_down(e, off, 64);
    if(tid==0) atomicAdd(&out[b], e);
}

extern "C" void kernel_launch(void* const* d_in, const int* in_sizes, int n_in,
                              void* d_out, int out_size, void* d_ws, size_t ws_size,
                              hipStream_t stream)
{
    const float* x     = (const float*)d_in[0];
    const float* cell  = (const float*)d_in[1];
    const float* rcell = (const float*)d_in[2];
    const float* sp_p  = (const float*)d_in[3];
    const float* gp    = (const float*)d_in[4];
    const float* bp    = (const float*)d_in[5];
    const float* fe_wi = (const float*)d_in[6];
    const float* fe_w  = (const float*)d_in[7];
    const float* fe_b  = (const float*)d_in[8];
    const float* fe_wo = (const float*)d_in[9];
    const float* fe_bo = (const float*)d_in[10];
    const int*   bdid  = (const int*)d_in[11];
    const int*   spec  = (const int*)d_in[12];
    float* out = (float*)d_out;

    // ws layout: claim table | counts | adjacency
    unsigned* table  = (unsigned*)d_ws;                       // 512*512 u32 (1 MiB)
    unsigned* counts = table + NATOMS*NATOMS;                 // 512 u32
    int*      adj    = (int*)(counts + NATOMS);               // 512*64 i32 (128 KiB)

    init_kernel <<<dim3(NBONDS/256), 256, 0, stream>>>(bdid, table, counts, out);
    claim_kernel<<<dim3(NBONDS/256), 256, 0, stream>>>(bdid, table);
    fill_kernel <<<dim3(NBONDS/256), 256, 0, stream>>>(bdid, table, counts, adj);
    bond_kernel <<<dim3(NBONDS/256, BATCH), 256, 0, stream>>>(
        x, cell, rcell, gp, bp, fe_wi, fe_w, fe_b, fe_wo, fe_bo, bdid, out);
    atom_kernel <<<dim3(NATOMS/64, BATCH), 64, 0, stream>>>(
        x, cell, rcell, sp_p, gp, bp, spec, counts, adj, out);
}